// Round 1
// baseline (679.489 us; speedup 1.0000x reference)
//
#include <hip/hip_runtime.h>

#define FDIM 128
#define HDIM 64
#define MSIZE 64
#define IMG_W 56
#define IMG_H 56
#define NPIX (IMG_W * IMG_H)
#define NB 8
#define NPTS 65536

// ---------------- transpose (B,C,H,W) -> (B, H*W, C) ----------------
__global__ __launch_bounds__(256) void transpose_feats(const float* __restrict__ in,
                                                       float* __restrict__ out) {
    __shared__ float tile[32][33];
    const int pt = blockIdx.x * 32;   // pixel tile base (3136 = 98*32)
    const int ct = blockIdx.y * 32;   // channel tile base (128 = 4*32)
    const int b  = blockIdx.z;
    const float* src = in  + (size_t)b * FDIM * NPIX;
    float*       dst = out + (size_t)b * NPIX * FDIM;
    const int tx = threadIdx.x, ty = threadIdx.y;
#pragma unroll
    for (int i = 0; i < 32; i += 8)
        tile[ty + i][tx] = src[(size_t)(ct + ty + i) * NPIX + (pt + tx)];
    __syncthreads();
#pragma unroll
    for (int i = 0; i < 32; i += 8)
        dst[(size_t)(pt + ty + i) * FDIM + (ct + tx)] = tile[tx][ty + i];
}

// ---------------- fused decoder: one thread per point ----------------
template <bool TR>
__global__ __launch_bounds__(64, 2) void decoder_kernel(
    const float* __restrict__ feats, const float* __restrict__ points,
    const float* __restrict__ Kmat, const float* __restrict__ Rt,
    const float* __restrict__ Bg,
    const float* __restrict__ W1, const float* __restrict__ b1,
    const float* __restrict__ W2, const float* __restrict__ b2,
    const float* __restrict__ W3, const float* __restrict__ b3,
    const float* __restrict__ W4, const float* __restrict__ b4,
    float* __restrict__ out) {
    // per-thread 64-float activation scratch; stride 65 -> bank (tid+i)%32, conflict-free
    __shared__ float hbuf[64 * 65];
    const int tid = threadIdx.x;
    const int b   = blockIdx.x / (NPTS / 64);  // uniform per block (1024 blocks/batch)
    const int gid = blockIdx.x * 64 + tid;

    // ---- load point ----
    const float px = points[(size_t)gid * 3 + 0];
    const float py = points[(size_t)gid * 3 + 1];
    const float pz = points[(size_t)gid * 3 + 2];

    // ---- camera projection (match reference op order in fp32) ----
    const float* rt = Rt + b * 12;   // (3,4) row-major
    const float* km = Kmat + b * 9;  // (3,3) row-major
    float cx = rt[0] * px + rt[1] * py + rt[2]  * pz + rt[3];
    float cy = rt[4] * px + rt[5] * py + rt[6]  * pz + rt[7];
    float cz = rt[8] * px + rt[9] * py + rt[10] * pz + rt[11];
    float ix = km[0] * cx + km[1] * cy + km[2] * cz;
    float iy = km[3] * cx + km[4] * cy + km[5] * cz;
    float iz = km[6] * cx + km[7] * cy + km[8] * cz;
    float z  = iz + 1e-8f;
    float u  = ix / z;              // IEEE divide, matches jnp
    float v  = iy / z;
    float valid = (iz > 0.0f) ? 1.0f : 0.0f;
    float u_norm = (2.0f * u + 1.0f) / (float)IMG_W - 1.0f;
    float v_norm = (2.0f * v + 1.0f) / (float)IMG_H - 1.0f;
    float x = ((u_norm + 1.0f) * (float)IMG_W - 1.0f) * 0.5f;
    float y = ((v_norm + 1.0f) * (float)IMG_H - 1.0f) * 0.5f;

    // ---- bilinear corner weights (fold inb mask + valid into weights) ----
    float x0f = floorf(x), y0f = floorf(y);
    float wx1 = x - x0f, wy1 = y - y0f;
    float wx0 = 1.0f - wx1, wy0 = 1.0f - wy1;
    int x0 = (int)x0f, y0 = (int)y0f;
    int x1 = x0 + 1, y1 = y0 + 1;
    int x0c = x0 < 0 ? 0 : (x0 > IMG_W - 1 ? IMG_W - 1 : x0);
    int x1c = x1 < 0 ? 0 : (x1 > IMG_W - 1 ? IMG_W - 1 : x1);
    int y0c = y0 < 0 ? 0 : (y0 > IMG_H - 1 ? IMG_H - 1 : y0);
    int y1c = y1 < 0 ? 0 : (y1 > IMG_H - 1 ? IMG_H - 1 : y1);
    float mx0 = (x0 >= 0 && x0 < IMG_W) ? 1.0f : 0.0f;
    float mx1 = (x1 >= 0 && x1 < IMG_W) ? 1.0f : 0.0f;
    float my0 = (y0 >= 0 && y0 < IMG_H) ? 1.0f : 0.0f;
    float my1 = (y1 >= 0 && y1 < IMG_H) ? 1.0f : 0.0f;
    float w00 = wx0 * wy0 * mx0 * my0 * valid;
    float w10 = wx1 * wy0 * mx1 * my0 * valid;
    float w01 = wx0 * wy1 * mx0 * my1 * valid;
    float w11 = wx1 * wy1 * mx1 * my1 * valid;

    // ---- layer 1 accumulators, init with bias ----
    float h[HDIM];
#pragma unroll
    for (int j = 0; j < HDIM; ++j) h[j] = b1[j];

    // ---- image features -> h1 ----
    if constexpr (TR) {
        const float* fb = feats + (size_t)b * NPIX * FDIM;
        const float4* f00 = (const float4*)(fb + (size_t)(y0c * IMG_W + x0c) * FDIM);
        const float4* f10 = (const float4*)(fb + (size_t)(y0c * IMG_W + x1c) * FDIM);
        const float4* f01 = (const float4*)(fb + (size_t)(y1c * IMG_W + x0c) * FDIM);
        const float4* f11 = (const float4*)(fb + (size_t)(y1c * IMG_W + x1c) * FDIM);
        // software-pipelined: prefetch next chunk's 4x float4 before FMA burst
        float4 a0 = f00[0], a1 = f10[0], a2 = f01[0], a3 = f11[0];
#pragma unroll 1
        for (int c4 = 0; c4 < FDIM / 4; ++c4) {
            float4 t0 = a0, t1 = a1, t2 = a2, t3 = a3;
            int nc = (c4 + 1) & (FDIM / 4 - 1);
            a0 = f00[nc]; a1 = f10[nc]; a2 = f01[nc]; a3 = f11[nc];
            float f0 = w00 * t0.x + w10 * t1.x + w01 * t2.x + w11 * t3.x;
            float f1 = w00 * t0.y + w10 * t1.y + w01 * t2.y + w11 * t3.y;
            float f2 = w00 * t0.z + w10 * t1.z + w01 * t2.z + w11 * t3.z;
            float f3 = w00 * t0.w + w10 * t1.w + w01 * t2.w + w11 * t3.w;
            const float* wr = W1 + (size_t)c4 * 4 * HDIM;  // uniform -> s_load
#pragma unroll
            for (int j = 0; j < HDIM; ++j) {
                float hj = h[j];
                hj = fmaf(f0, wr[0 * HDIM + j], hj);
                hj = fmaf(f1, wr[1 * HDIM + j], hj);
                hj = fmaf(f2, wr[2 * HDIM + j], hj);
                hj = fmaf(f3, wr[3 * HDIM + j], hj);
                h[j] = hj;
            }
        }
    } else {
        const float* fb = feats + (size_t)b * FDIM * NPIX;
        const int p00 = y0c * IMG_W + x0c, p10 = y0c * IMG_W + x1c;
        const int p01 = y1c * IMG_W + x0c, p11 = y1c * IMG_W + x1c;
#pragma unroll 1
        for (int c = 0; c < FDIM; ++c) {
            const float* fp = fb + (size_t)c * NPIX;
            float fv = w00 * fp[p00] + w10 * fp[p10] + w01 * fp[p01] + w11 * fp[p11];
            const float* wr = W1 + (size_t)c * HDIM;
#pragma unroll
            for (int j = 0; j < HDIM; ++j) h[j] = fmaf(fv, wr[j], h[j]);
        }
    }

    // ---- Fourier features -> h1 ----
    // x_proj = 2*pi*(p . Bg[m]); sin(2*pi*t) == v_sin_f32(fract(t))  (HW takes revolutions)
#pragma unroll 1
    for (int m = 0; m < MSIZE; ++m) {
        float t = Bg[m * 3 + 0] * px + Bg[m * 3 + 1] * py + Bg[m * 3 + 2] * pz;
        float tf = t - floorf(t);
        float s = __builtin_amdgcn_sinf(tf);
        float c = __builtin_amdgcn_cosf(tf);
        const float* ws = W1 + (size_t)(FDIM + m) * HDIM;          // sin rows
        const float* wc = W1 + (size_t)(FDIM + MSIZE + m) * HDIM;  // cos rows
#pragma unroll
        for (int j = 0; j < HDIM; ++j)
            h[j] = fmaf(s, ws[j], fmaf(c, wc[j], h[j]));
    }

    // ---- relu, stage h1 to private LDS slice (no cross-thread sharing -> no barrier) ----
    float* myh = &hbuf[tid * 65];
#pragma unroll
    for (int j = 0; j < HDIM; ++j) myh[j] = fmaxf(h[j], 0.0f);

    // ---- layer 2 ----
    float h2[HDIM];
#pragma unroll
    for (int j = 0; j < HDIM; ++j) h2[j] = b2[j];
#pragma unroll 1
    for (int i = 0; i < HDIM; ++i) {
        float hi = myh[i];
        const float* wr = W2 + (size_t)i * HDIM;
#pragma unroll
        for (int j = 0; j < HDIM; ++j) h2[j] = fmaf(hi, wr[j], h2[j]);
    }
#pragma unroll
    for (int j = 0; j < HDIM; ++j) myh[j] = fmaxf(h2[j], 0.0f);

    // ---- layer 3 (accumulate back into h regs) ----
#pragma unroll
    for (int j = 0; j < HDIM; ++j) h[j] = b3[j];
#pragma unroll 1
    for (int i = 0; i < HDIM; ++i) {
        float hi = myh[i];
        const float* wr = W3 + (size_t)i * HDIM;
#pragma unroll
        for (int j = 0; j < HDIM; ++j) h[j] = fmaf(hi, wr[j], h[j]);
    }

    // ---- layer 4 ----
    float acc = b4[0];
#pragma unroll
    for (int j = 0; j < HDIM; ++j) acc = fmaf(fmaxf(h[j], 0.0f), W4[j], acc);

    out[gid] = acc;
}

extern "C" void kernel_launch(void* const* d_in, const int* in_sizes, int n_in,
                              void* d_out, int out_size, void* d_ws, size_t ws_size,
                              hipStream_t stream) {
    const float* feats = (const float*)d_in[0];
    const float* pts   = (const float*)d_in[1];
    const float* k     = (const float*)d_in[2];
    const float* rt    = (const float*)d_in[3];
    const float* Bg    = (const float*)d_in[4];
    const float* W1    = (const float*)d_in[5];
    const float* b1    = (const float*)d_in[6];
    const float* W2    = (const float*)d_in[7];
    const float* b2    = (const float*)d_in[8];
    const float* W3    = (const float*)d_in[9];
    const float* b3    = (const float*)d_in[10];
    const float* W4    = (const float*)d_in[11];
    const float* b4    = (const float*)d_in[12];
    float* out = (float*)d_out;

    const size_t needed = (size_t)NB * NPIX * FDIM * sizeof(float);
    const dim3 grid(NB * NPTS / 64), block(64);
    if (ws_size >= needed) {
        float* ft = (float*)d_ws;
        transpose_feats<<<dim3(NPIX / 32, FDIM / 32, NB), dim3(32, 8), 0, stream>>>(feats, ft);
        decoder_kernel<true><<<grid, block, 0, stream>>>(ft, pts, k, rt, Bg,
                                                         W1, b1, W2, b2, W3, b3, W4, b4, out);
    } else {
        decoder_kernel<false><<<grid, block, 0, stream>>>(feats, pts, k, rt, Bg,
                                                          W1, b1, W2, b2, W3, b3, W4, b4, out);
    }
}

// Round 2
// 235.382 us; speedup vs baseline: 2.8868x; 2.8868x over previous
//
#include <hip/hip_runtime.h>

#define FDIM 128
#define HDIM 64
#define MSIZE 64
#define IMG_W 56
#define IMG_H 56
#define NPIX (IMG_W * IMG_H)
#define NB 8
#define NPTS 65536

typedef _Float16 f16x8 __attribute__((ext_vector_type(8)));
typedef float f32x4 __attribute__((ext_vector_type(4)));

// d_ws layout:
//   [0      , 32768) bytes : W1 fragments, fp16, 8kt*4nt*64lane*8
//   [32768  , 40960) bytes : W2 fragments, 2kt*4nt*64*8
//   [40960  , 49152) bytes : W3 fragments
//   [49152  , +12.8MB)     : transposed features (B, H*W, C) fp32
#define W2_OFF 16384   // in _Float16 units
#define W3_OFF 20480
#define FT_BYTE_OFF 49152

// ---------------- transpose (B,C,H,W) -> (B, H*W, C) ----------------
__global__ __launch_bounds__(256) void transpose_feats(const float* __restrict__ in,
                                                       float* __restrict__ out) {
    __shared__ float tile[32][33];
    const int pt = blockIdx.x * 32;
    const int ct = blockIdx.y * 32;
    const int b  = blockIdx.z;
    const float* src = in  + (size_t)b * FDIM * NPIX;
    float*       dst = out + (size_t)b * NPIX * FDIM;
    const int tx = threadIdx.x, ty = threadIdx.y;
#pragma unroll
    for (int i = 0; i < 32; i += 8)
        tile[ty + i][tx] = src[(size_t)(ct + ty + i) * NPIX + (pt + tx)];
    __syncthreads();
#pragma unroll
    for (int i = 0; i < 32; i += 8)
        dst[(size_t)(pt + ty + i) * FDIM + (ct + tx)] = tile[tx][ty + i];
}

// ---------------- pack W1/W2/W3 into MFMA B-fragment order (fp16) ----------------
// frag element j of lane l for tile (kt,nt): B[k = kt*32 + (l>>4)*8 + j][n = nt*16 + (l&15)]
// W1 k-permutation: k<128 -> img channel k; k>=128 -> m=(k-128)>>1, t=k&1 -> row 128+t*64+m
// (A-gen interleaves sin/cos per frequency; this must match exactly.)
__global__ __launch_bounds__(256) void pack_weights(const float* __restrict__ W1,
                                                    const float* __restrict__ W2,
                                                    const float* __restrict__ W3,
                                                    _Float16* __restrict__ ws) {
    const int t = blockIdx.x * 256 + threadIdx.x;  // 0..3071
    if (t >= 3072) return;
    const int l = t & 63;
    const int q = l >> 4;
    const int col = l & 15;
    const int frag = t >> 6;  // 0..47
    if (frag < 32) {          // W1: kt 0..7, nt 0..3
        const int kt = frag >> 2, nt = frag & 3;
#pragma unroll
        for (int j = 0; j < 8; ++j) {
            int k = kt * 32 + q * 8 + j;
            int row = (k < 128) ? k : (128 + (k & 1) * 64 + ((k - 128) >> 1));
            ws[((size_t)(frag * 64 + l)) * 8 + j] = (_Float16)W1[row * HDIM + nt * 16 + col];
        }
    } else if (frag < 40) {   // W2: kt 0..1, nt 0..3
        const int f2 = frag - 32;
        const int kt = f2 >> 2, nt = f2 & 3;
#pragma unroll
        for (int j = 0; j < 8; ++j) {
            int row = kt * 32 + q * 8 + j;
            ws[W2_OFF + ((size_t)(f2 * 64 + l)) * 8 + j] = (_Float16)W2[row * HDIM + nt * 16 + col];
        }
    } else {                  // W3
        const int f3 = frag - 40;
        const int kt = f3 >> 2, nt = f3 & 3;
#pragma unroll
        for (int j = 0; j < 8; ++j) {
            int row = kt * 32 + q * 8 + j;
            ws[W3_OFF + ((size_t)(f3 * 64 + l)) * 8 + j] = (_Float16)W3[row * HDIM + nt * 16 + col];
        }
    }
}

// ---------------- main fused decoder: 1 wave = 64 points, fp16 MFMA MLP ----------------
template <bool TR>
__global__ __launch_bounds__(64) void decoder_mfma(
    const float* __restrict__ feats,  // TR ? (B,HW,C) transposed : (B,C,H,W) original
    const float* __restrict__ points,
    const float* __restrict__ Kmat, const float* __restrict__ Rt,
    const float* __restrict__ Bg,
    const _Float16* __restrict__ wfrag,
    const float* __restrict__ b1, const float* __restrict__ b2,
    const float* __restrict__ b3,
    const float* __restrict__ W4, const float* __restrict__ b4,
    float* __restrict__ out) {
    // A/H tile: 64 rows x 72 halves (pad 8 -> row stride 144B, 16B-aligned, b128 at BW floor)
    __shared__ _Float16 Abuf[64 * 72];
    const int l = threadIdx.x;
    const int q = l >> 4;
    const int col = l & 15;
    const int base = blockIdx.x * 64;
    const int b = blockIdx.x >> 10;  // 1024 blocks per batch (65536/64)
    const int gid = base + l;

    // ---- load point ----
    const float px = points[(size_t)gid * 3 + 0];
    const float py = points[(size_t)gid * 3 + 1];
    const float pz = points[(size_t)gid * 3 + 2];

    // ---- camera projection (identical fp32 chain to verified R1) ----
    const float* rt = Rt + b * 12;
    const float* km = Kmat + b * 9;
    float cx = rt[0] * px + rt[1] * py + rt[2]  * pz + rt[3];
    float cy = rt[4] * px + rt[5] * py + rt[6]  * pz + rt[7];
    float cz = rt[8] * px + rt[9] * py + rt[10] * pz + rt[11];
    float ix = km[0] * cx + km[1] * cy + km[2] * cz;
    float iy = km[3] * cx + km[4] * cy + km[5] * cz;
    float iz = km[6] * cx + km[7] * cy + km[8] * cz;
    float z  = iz + 1e-8f;
    float u  = ix / z;
    float v  = iy / z;
    float valid = (iz > 0.0f) ? 1.0f : 0.0f;
    float u_norm = (2.0f * u + 1.0f) / (float)IMG_W - 1.0f;
    float v_norm = (2.0f * v + 1.0f) / (float)IMG_H - 1.0f;
    float x = ((u_norm + 1.0f) * (float)IMG_W - 1.0f) * 0.5f;
    float y = ((v_norm + 1.0f) * (float)IMG_H - 1.0f) * 0.5f;

    float x0f = floorf(x), y0f = floorf(y);
    float wx1 = x - x0f, wy1 = y - y0f;
    float wx0 = 1.0f - wx1, wy0 = 1.0f - wy1;
    int x0 = (int)x0f, y0 = (int)y0f;
    int x1 = x0 + 1, y1 = y0 + 1;
    int x0c = x0 < 0 ? 0 : (x0 > IMG_W - 1 ? IMG_W - 1 : x0);
    int x1c = x1 < 0 ? 0 : (x1 > IMG_W - 1 ? IMG_W - 1 : x1);
    int y0c = y0 < 0 ? 0 : (y0 > IMG_H - 1 ? IMG_H - 1 : y0);
    int y1c = y1 < 0 ? 0 : (y1 > IMG_H - 1 ? IMG_H - 1 : y1);
    float mx0 = (x0 >= 0 && x0 < IMG_W) ? 1.0f : 0.0f;
    float mx1 = (x1 >= 0 && x1 < IMG_W) ? 1.0f : 0.0f;
    float my0 = (y0 >= 0 && y0 < IMG_H) ? 1.0f : 0.0f;
    float my1 = (y1 >= 0 && y1 < IMG_H) ? 1.0f : 0.0f;
    float w00 = wx0 * wy0 * mx0 * my0 * valid;
    float w10 = wx1 * wy0 * mx1 * my0 * valid;
    float w01 = wx0 * wy1 * mx0 * my1 * valid;
    float w11 = wx1 * wy1 * mx1 * my1 * valid;

    const int p00i = y0c * IMG_W + x0c, p10i = y0c * IMG_W + x1c;
    const int p01i = y1c * IMG_W + x0c, p11i = y1c * IMG_W + x1c;

    const f32x4 zero4 = {0.0f, 0.0f, 0.0f, 0.0f};
    f32x4 acc[4][4];
#pragma unroll
    for (int mt = 0; mt < 4; ++mt)
#pragma unroll
        for (int nt = 0; nt < 4; ++nt) acc[mt][nt] = zero4;

    // ================= layer 1: K=256 in 4 chunks of 64 =================
#pragma unroll 1
    for (int kc = 0; kc < 4; ++kc) {
        if (kc < 2) {
            const int ch0 = kc * 64;
            if constexpr (TR) {
                const float* fb = feats + (size_t)b * NPIX * FDIM + ch0;
                const float* F00 = fb + (size_t)p00i * FDIM;
                const float* F10 = fb + (size_t)p10i * FDIM;
                const float* F01 = fb + (size_t)p01i * FDIM;
                const float* F11 = fb + (size_t)p11i * FDIM;
#pragma unroll
                for (int g = 0; g < 8; ++g) {
                    f32x4 a00 = ((const f32x4*)(F00 + g * 8))[0];
                    f32x4 c00 = ((const f32x4*)(F00 + g * 8))[1];
                    f32x4 a10 = ((const f32x4*)(F10 + g * 8))[0];
                    f32x4 c10 = ((const f32x4*)(F10 + g * 8))[1];
                    f32x4 a01 = ((const f32x4*)(F01 + g * 8))[0];
                    f32x4 c01 = ((const f32x4*)(F01 + g * 8))[1];
                    f32x4 a11 = ((const f32x4*)(F11 + g * 8))[0];
                    f32x4 c11 = ((const f32x4*)(F11 + g * 8))[1];
                    f16x8 vv;
#pragma unroll
                    for (int i = 0; i < 4; ++i) {
                        float r0 = w00 * a00[i] + w10 * a10[i] + w01 * a01[i] + w11 * a11[i];
                        float r1 = w00 * c00[i] + w10 * c10[i] + w01 * c01[i] + w11 * c11[i];
                        vv[i] = (_Float16)r0;
                        vv[i + 4] = (_Float16)r1;
                    }
                    *(f16x8*)(&Abuf[l * 72 + g * 8]) = vv;
                }
            } else {
                const float* fb = feats + (size_t)b * FDIM * NPIX;
#pragma unroll
                for (int g = 0; g < 8; ++g) {
                    f16x8 vv;
#pragma unroll
                    for (int i = 0; i < 8; ++i) {
                        const float* fp = fb + (size_t)(ch0 + g * 8 + i) * NPIX;
                        float r = w00 * fp[p00i] + w10 * fp[p10i] + w01 * fp[p01i] + w11 * fp[p11i];
                        vv[i] = (_Float16)r;
                    }
                    *(f16x8*)(&Abuf[l * 72 + g * 8]) = vv;
                }
            }
        } else {
            // Fourier dims, interleaved (sin_m, cos_m) pairs; matches pack_weights perm
            const int mb = (kc - 2) * 32;
#pragma unroll
            for (int g = 0; g < 8; ++g) {
                f16x8 vv;
#pragma unroll
                for (int i = 0; i < 4; ++i) {
                    const int m = mb + g * 4 + i;
                    float t = Bg[m * 3 + 0] * px + Bg[m * 3 + 1] * py + Bg[m * 3 + 2] * pz;
                    float tf = t - floorf(t);
                    vv[2 * i]     = (_Float16)__builtin_amdgcn_sinf(tf);
                    vv[2 * i + 1] = (_Float16)__builtin_amdgcn_cosf(tf);
                }
                *(f16x8*)(&Abuf[l * 72 + g * 8]) = vv;
            }
        }
        __syncthreads();
#pragma unroll
        for (int ktl = 0; ktl < 2; ++ktl) {
            const int ktg = kc * 2 + ktl;
            f16x8 bf[4];
#pragma unroll
            for (int nt = 0; nt < 4; ++nt)
                bf[nt] = *(const f16x8*)(wfrag + ((size_t)((ktg * 4 + nt) * 64 + l)) * 8);
#pragma unroll
            for (int mt = 0; mt < 4; ++mt) {
                f16x8 af = *(const f16x8*)(&Abuf[(mt * 16 + col) * 72 + ktl * 32 + q * 8]);
#pragma unroll
                for (int nt = 0; nt < 4; ++nt)
                    acc[mt][nt] = __builtin_amdgcn_mfma_f32_16x16x32_f16(af, bf[nt], acc[mt][nt], 0, 0, 0);
            }
        }
        __syncthreads();
    }

    // ---- L1 epilogue: +b1, relu, store h1 in A-layout fp16 ----
    float bb[4];
#pragma unroll
    for (int nt = 0; nt < 4; ++nt) bb[nt] = b1[nt * 16 + col];
#pragma unroll
    for (int mt = 0; mt < 4; ++mt)
#pragma unroll
        for (int nt = 0; nt < 4; ++nt)
#pragma unroll
            for (int r = 0; r < 4; ++r) {
                float hv = fmaxf(acc[mt][nt][r] + bb[nt], 0.0f);
                Abuf[(mt * 16 + q * 4 + r) * 72 + nt * 16 + col] = (_Float16)hv;
            }
    __syncthreads();

    // ================= layer 2 =================
    f32x4 acc2[4][4];
#pragma unroll
    for (int mt = 0; mt < 4; ++mt)
#pragma unroll
        for (int nt = 0; nt < 4; ++nt) acc2[mt][nt] = zero4;
#pragma unroll
    for (int ktl = 0; ktl < 2; ++ktl) {
        f16x8 bf[4];
#pragma unroll
        for (int nt = 0; nt < 4; ++nt)
            bf[nt] = *(const f16x8*)(wfrag + W2_OFF + ((size_t)((ktl * 4 + nt) * 64 + l)) * 8);
#pragma unroll
        for (int mt = 0; mt < 4; ++mt) {
            f16x8 af = *(const f16x8*)(&Abuf[(mt * 16 + col) * 72 + ktl * 32 + q * 8]);
#pragma unroll
            for (int nt = 0; nt < 4; ++nt)
                acc2[mt][nt] = __builtin_amdgcn_mfma_f32_16x16x32_f16(af, bf[nt], acc2[mt][nt], 0, 0, 0);
        }
    }
    __syncthreads();
#pragma unroll
    for (int nt = 0; nt < 4; ++nt) bb[nt] = b2[nt * 16 + col];
#pragma unroll
    for (int mt = 0; mt < 4; ++mt)
#pragma unroll
        for (int nt = 0; nt < 4; ++nt)
#pragma unroll
            for (int r = 0; r < 4; ++r) {
                float hv = fmaxf(acc2[mt][nt][r] + bb[nt], 0.0f);
                Abuf[(mt * 16 + q * 4 + r) * 72 + nt * 16 + col] = (_Float16)hv;
            }
    __syncthreads();

    // ================= layer 3 (reuse acc) =================
#pragma unroll
    for (int mt = 0; mt < 4; ++mt)
#pragma unroll
        for (int nt = 0; nt < 4; ++nt) acc[mt][nt] = zero4;
#pragma unroll
    for (int ktl = 0; ktl < 2; ++ktl) {
        f16x8 bf[4];
#pragma unroll
        for (int nt = 0; nt < 4; ++nt)
            bf[nt] = *(const f16x8*)(wfrag + W3_OFF + ((size_t)((ktl * 4 + nt) * 64 + l)) * 8);
#pragma unroll
        for (int mt = 0; mt < 4; ++mt) {
            f16x8 af = *(const f16x8*)(&Abuf[(mt * 16 + col) * 72 + ktl * 32 + q * 8]);
#pragma unroll
            for (int nt = 0; nt < 4; ++nt)
                acc[mt][nt] = __builtin_amdgcn_mfma_f32_16x16x32_f16(af, bf[nt], acc[mt][nt], 0, 0, 0);
        }
    }

    // ================= layer 4: per-lane partial + 16-lane shfl reduction =================
    float b3v[4], w4v[4];
#pragma unroll
    for (int nt = 0; nt < 4; ++nt) {
        b3v[nt] = b3[nt * 16 + col];
        w4v[nt] = W4[nt * 16 + col];
    }
    const float b4v = b4[0];
#pragma unroll
    for (int mt = 0; mt < 4; ++mt)
#pragma unroll
        for (int r = 0; r < 4; ++r) {
            float p = 0.0f;
#pragma unroll
            for (int nt = 0; nt < 4; ++nt)
                p = fmaf(fmaxf(acc[mt][nt][r] + b3v[nt], 0.0f), w4v[nt], p);
            p += __shfl_xor(p, 1);
            p += __shfl_xor(p, 2);
            p += __shfl_xor(p, 4);
            p += __shfl_xor(p, 8);
            if (col == 0) out[base + mt * 16 + q * 4 + r] = p + b4v;
        }
}

// ---------------- fallback: verified R1 pure-VALU kernel ----------------
__global__ __launch_bounds__(64, 2) void decoder_valu(
    const float* __restrict__ feats, const float* __restrict__ points,
    const float* __restrict__ Kmat, const float* __restrict__ Rt,
    const float* __restrict__ Bg,
    const float* __restrict__ W1, const float* __restrict__ b1,
    const float* __restrict__ W2, const float* __restrict__ b2,
    const float* __restrict__ W3, const float* __restrict__ b3,
    const float* __restrict__ W4, const float* __restrict__ b4,
    float* __restrict__ out) {
    __shared__ float hbuf[64 * 65];
    const int tid = threadIdx.x;
    const int b   = blockIdx.x / (NPTS / 64);
    const int gid = blockIdx.x * 64 + tid;
    const float px = points[(size_t)gid * 3 + 0];
    const float py = points[(size_t)gid * 3 + 1];
    const float pz = points[(size_t)gid * 3 + 2];
    const float* rt = Rt + b * 12;
    const float* km = Kmat + b * 9;
    float cx = rt[0] * px + rt[1] * py + rt[2]  * pz + rt[3];
    float cy = rt[4] * px + rt[5] * py + rt[6]  * pz + rt[7];
    float cz = rt[8] * px + rt[9] * py + rt[10] * pz + rt[11];
    float ix = km[0] * cx + km[1] * cy + km[2] * cz;
    float iy = km[3] * cx + km[4] * cy + km[5] * cz;
    float iz = km[6] * cx + km[7] * cy + km[8] * cz;
    float z  = iz + 1e-8f;
    float u  = ix / z, v = iy / z;
    float valid = (iz > 0.0f) ? 1.0f : 0.0f;
    float u_norm = (2.0f * u + 1.0f) / (float)IMG_W - 1.0f;
    float v_norm = (2.0f * v + 1.0f) / (float)IMG_H - 1.0f;
    float x = ((u_norm + 1.0f) * (float)IMG_W - 1.0f) * 0.5f;
    float y = ((v_norm + 1.0f) * (float)IMG_H - 1.0f) * 0.5f;
    float x0f = floorf(x), y0f = floorf(y);
    float wx1 = x - x0f, wy1 = y - y0f;
    float wx0 = 1.0f - wx1, wy0 = 1.0f - wy1;
    int x0 = (int)x0f, y0 = (int)y0f;
    int x1 = x0 + 1, y1 = y0 + 1;
    int x0c = x0 < 0 ? 0 : (x0 > IMG_W - 1 ? IMG_W - 1 : x0);
    int x1c = x1 < 0 ? 0 : (x1 > IMG_W - 1 ? IMG_W - 1 : x1);
    int y0c = y0 < 0 ? 0 : (y0 > IMG_H - 1 ? IMG_H - 1 : y0);
    int y1c = y1 < 0 ? 0 : (y1 > IMG_H - 1 ? IMG_H - 1 : y1);
    float mx0 = (x0 >= 0 && x0 < IMG_W) ? 1.0f : 0.0f;
    float mx1 = (x1 >= 0 && x1 < IMG_W) ? 1.0f : 0.0f;
    float my0 = (y0 >= 0 && y0 < IMG_H) ? 1.0f : 0.0f;
    float my1 = (y1 >= 0 && y1 < IMG_H) ? 1.0f : 0.0f;
    float w00 = wx0 * wy0 * mx0 * my0 * valid;
    float w10 = wx1 * wy0 * mx1 * my0 * valid;
    float w01 = wx0 * wy1 * mx0 * my1 * valid;
    float w11 = wx1 * wy1 * mx1 * my1 * valid;
    float h[HDIM];
#pragma unroll
    for (int j = 0; j < HDIM; ++j) h[j] = b1[j];
    const float* fb = feats + (size_t)b * FDIM * NPIX;
    const int p00 = y0c * IMG_W + x0c, p10 = y0c * IMG_W + x1c;
    const int p01 = y1c * IMG_W + x0c, p11 = y1c * IMG_W + x1c;
#pragma unroll 1
    for (int c = 0; c < FDIM; ++c) {
        const float* fp = fb + (size_t)c * NPIX;
        float fv = w00 * fp[p00] + w10 * fp[p10] + w01 * fp[p01] + w11 * fp[p11];
        const float* wr = W1 + (size_t)c * HDIM;
#pragma unroll
        for (int j = 0; j < HDIM; ++j) h[j] = fmaf(fv, wr[j], h[j]);
    }
#pragma unroll 1
    for (int m = 0; m < MSIZE; ++m) {
        float t = Bg[m * 3 + 0] * px + Bg[m * 3 + 1] * py + Bg[m * 3 + 2] * pz;
        float tf = t - floorf(t);
        float s = __builtin_amdgcn_sinf(tf);
        float c = __builtin_amdgcn_cosf(tf);
        const float* wsn = W1 + (size_t)(FDIM + m) * HDIM;
        const float* wcs = W1 + (size_t)(FDIM + MSIZE + m) * HDIM;
#pragma unroll
        for (int j = 0; j < HDIM; ++j)
            h[j] = fmaf(s, wsn[j], fmaf(c, wcs[j], h[j]));
    }
    float* myh = &hbuf[tid * 65];
#pragma unroll
    for (int j = 0; j < HDIM; ++j) myh[j] = fmaxf(h[j], 0.0f);
    float h2[HDIM];
#pragma unroll
    for (int j = 0; j < HDIM; ++j) h2[j] = b2[j];
#pragma unroll 1
    for (int i = 0; i < HDIM; ++i) {
        float hi = myh[i];
        const float* wr = W2 + (size_t)i * HDIM;
#pragma unroll
        for (int j = 0; j < HDIM; ++j) h2[j] = fmaf(hi, wr[j], h2[j]);
    }
#pragma unroll
    for (int j = 0; j < HDIM; ++j) myh[j] = fmaxf(h2[j], 0.0f);
#pragma unroll
    for (int j = 0; j < HDIM; ++j) h[j] = b3[j];
#pragma unroll 1
    for (int i = 0; i < HDIM; ++i) {
        float hi = myh[i];
        const float* wr = W3 + (size_t)i * HDIM;
#pragma unroll
        for (int j = 0; j < HDIM; ++j) h[j] = fmaf(hi, wr[j], h[j]);
    }
    float acc = b4[0];
#pragma unroll
    for (int j = 0; j < HDIM; ++j) acc = fmaf(fmaxf(h[j], 0.0f), W4[j], acc);
    out[gid] = acc;
}

extern "C" void kernel_launch(void* const* d_in, const int* in_sizes, int n_in,
                              void* d_out, int out_size, void* d_ws, size_t ws_size,
                              hipStream_t stream) {
    const float* feats = (const float*)d_in[0];
    const float* pts   = (const float*)d_in[1];
    const float* k     = (const float*)d_in[2];
    const float* rt    = (const float*)d_in[3];
    const float* Bg    = (const float*)d_in[4];
    const float* W1    = (const float*)d_in[5];
    const float* b1    = (const float*)d_in[6];
    const float* W2    = (const float*)d_in[7];
    const float* b2    = (const float*)d_in[8];
    const float* W3    = (const float*)d_in[9];
    const float* b3    = (const float*)d_in[10];
    const float* W4    = (const float*)d_in[11];
    const float* b4    = (const float*)d_in[12];
    float* out = (float*)d_out;

    const size_t ftBytes = (size_t)NB * NPIX * FDIM * sizeof(float);
    const size_t fragBytes = FT_BYTE_OFF;

    if (ws_size >= fragBytes + ftBytes) {
        _Float16* wf = (_Float16*)d_ws;
        float* ft = (float*)((char*)d_ws + FT_BYTE_OFF);
        pack_weights<<<12, 256, 0, stream>>>(W1, W2, W3, wf);
        transpose_feats<<<dim3(NPIX / 32, FDIM / 32, NB), dim3(32, 8), 0, stream>>>(feats, ft);
        decoder_mfma<true><<<NB * NPTS / 64, 64, 0, stream>>>(ft, pts, k, rt, Bg, wf,
                                                              b1, b2, b3, W4, b4, out);
    } else if (ws_size >= fragBytes) {
        _Float16* wf = (_Float16*)d_ws;
        pack_weights<<<12, 256, 0, stream>>>(W1, W2, W3, wf);
        decoder_mfma<false><<<NB * NPTS / 64, 64, 0, stream>>>(feats, pts, k, rt, Bg, wf,
                                                               b1, b2, b3, W4, b4, out);
    } else {
        decoder_valu<<<NB * NPTS / 64, 64, 0, stream>>>(feats, pts, k, rt, Bg,
                                                        W1, b1, W2, b2, W3, b3, W4, b4, out);
    }
}